// Round 8
// baseline (504.380 us; speedup 1.0000x reference)
//
#include <hip/hip_runtime.h>
#include <hip/hip_bf16.h>

#define NN 50000
#define EE 600000
#define DD 128
#define RR 7
#define SS 8            // R + self-loop slot
#define KK 1024         // SS*DD
#define GG 32
#define BM 128
#define NSEG (NN * RR)  // 350000 CSR segments
#define NB1 ((NSEG + 1023) / 1024)   // 342 scan blocks

typedef float f32x4 __attribute__((ext_vector_type(4)));
typedef short short8 __attribute__((ext_vector_type(8)));
typedef unsigned short u16x8 __attribute__((ext_vector_type(8)));

static __device__ __forceinline__ unsigned short f2bf(float f) {
    union { float f; unsigned u; } v; v.f = f;
    unsigned r = v.u + 0x7fff + ((v.u >> 16) & 1);
    return (unsigned short)(r >> 16);
}
static __device__ __forceinline__ float bf2f(unsigned short u) {
    union { unsigned u; float f; } v; v.u = ((unsigned)u) << 16;
    return v.f;
}

// ---------------- weights prep: W^T bf16 [j][k], bias = lin_b + sl_b ----------------
__global__ void prep_w(const float* __restrict__ lin_w, const float* __restrict__ sl_w,
                       const float* __restrict__ lin_b, const float* __restrict__ sl_b,
                       unsigned short* __restrict__ Wt, float* __restrict__ bias) {
    int idx = blockIdx.x * 256 + threadIdx.x;
    if (idx < DD) bias[idx] = lin_b[idx] + sl_b[idx];
    if (idx >= DD * KK) return;
    int j  = idx >> 10;
    int kk = idx & 1023;
    float w = (kk < RR * DD) ? lin_w[kk * DD + j] : sl_w[(kk - RR * DD) * DD + j];
    Wt[(size_t)j * KK + kk] = f2bf(w);
}

// ---------------- CSR build ----------------
__global__ void zero_ints(int* __restrict__ p, int n) {
    int i = blockIdx.x * 256 + threadIdx.x;
    if (i < n) p[i] = 0;
}

__global__ void hist(const int* __restrict__ node_out, const int* __restrict__ rel,
                     int* __restrict__ counts) {
    int e = blockIdx.x * 256 + threadIdx.x;
    if (e >= EE) return;
    atomicAdd(&counts[node_out[e] * RR + rel[e]], 1);
}

__global__ __launch_bounds__(256) void scan1(const int* __restrict__ counts,
                                             int* __restrict__ start, int* __restrict__ bsum) {
    __shared__ int s[256];
    int tid = threadIdx.x;
    int base = blockIdx.x * 1024 + tid * 4;
    int v[4], sum = 0;
    #pragma unroll
    for (int j = 0; j < 4; ++j) {
        v[j] = (base + j < NSEG) ? counts[base + j] : 0;
        sum += v[j];
    }
    s[tid] = sum; __syncthreads();
    for (int off = 1; off < 256; off <<= 1) {
        int t = (tid >= off) ? s[tid - off] : 0;
        __syncthreads();
        s[tid] += t;
        __syncthreads();
    }
    int run = s[tid] - sum;
    if (tid == 255) bsum[blockIdx.x] = s[255];
    #pragma unroll
    for (int j = 0; j < 4; ++j) {
        if (base + j < NSEG) { start[base + j] = run; run += v[j]; }
    }
}

__global__ __launch_bounds__(512) void scan2(int* __restrict__ bsum) {
    __shared__ int s[512];
    int tid = threadIdx.x;
    int v = (tid < NB1) ? bsum[tid] : 0;
    s[tid] = v; __syncthreads();
    for (int off = 1; off < 512; off <<= 1) {
        int t = (tid >= off) ? s[tid - off] : 0;
        __syncthreads();
        s[tid] += t;
        __syncthreads();
    }
    if (tid < NB1) bsum[tid] = s[tid] - v;
}

// segd[i] = {global start, count}
__global__ void scan3(const int* __restrict__ start, const int* __restrict__ bsum,
                      const int* __restrict__ counts, int2* __restrict__ segd) {
    int i = blockIdx.x * 256 + threadIdx.x;
    if (i < NSEG) segd[i] = make_int2(start[i] + bsum[i >> 10], counts[i]);
}

__global__ void fill(const int* __restrict__ node_in, const int* __restrict__ node_out,
                     const int* __restrict__ rel, const float* __restrict__ ew,
                     const int2* __restrict__ segd, int* __restrict__ cursor,
                     int2* __restrict__ edges) {
    int e = blockIdx.x * 256 + threadIdx.x;
    if (e >= EE) return;
    int seg = node_out[e] * RR + rel[e];
    int pos = segd[seg].x + atomicAdd(&cursor[seg], 1);
    edges[pos] = make_int2(node_in[e], __float_as_int(ew[e]));
}

// layer-0 bf16 shadow of x.  EXACTLY NN*32 threads.
__global__ void init_hb(const float* __restrict__ x, unsigned short* __restrict__ hb) {
    int t = blockIdx.x * 256 + threadIdx.x;     // [0, NN*32)
    if (t >= NN * 32) return;
    f32x4 v = ((const f32x4*)x)[t];
    unsigned short o[4] = { f2bf(v.x), f2bf(v.y), f2bf(v.z), f2bf(v.w) };
    *(ulong1*)nullptr;   // (unused placeholder removed below)
}

// ---------------- fused layer: gather-build A slot tiles in LDS + MFMA ----------------
// block = 128 nodes, 256 threads (4 waves).  LDS: sA 32 KB (XOR-swizzled) + sSeg 7 KB.
__global__ __launch_bounds__(256) void fused_layer(
        const unsigned short* __restrict__ hb,       // bf16 h  [N][128]
        const int2* __restrict__ segd,
        const int2* __restrict__ edges,
        const unsigned short* __restrict__ Wt,       // [128 j][1024 k]
        const float* __restrict__ bias,
        const float* __restrict__ hprev,             // fp32 h  [N][128]
        float* __restrict__ hout,
        unsigned short* __restrict__ hb_next,
        int write_next) {
    __shared__ unsigned short sA[BM * DD];           // [row][chunk^swz], chunk = 8 bf16
    __shared__ int2 sSeg[BM * RR];
    int tid = threadIdx.x;
    int bm0 = blockIdx.x * BM;

    for (int i = tid; i < BM * RR; i += 256) {
        int gs = bm0 * RR + i;
        sSeg[i] = (gs < NSEG) ? segd[gs] : make_int2(0, 0);
    }

    int wid = tid >> 6, lane = tid & 63;
    int wr = wid >> 1, wc = wid & 1;
    int lm = lane & 15, lg = lane >> 4;
    int grp = tid >> 3, gl = tid & 7;                // 32 gather groups x 8 lanes

    f32x4 acc[4][4] = {};
    __syncthreads();

    for (int s = 0; s < SS; ++s) {
        // ---- gather/stage A tile for slot s ----
        #pragma unroll
        for (int rr4 = 0; rr4 < 4; ++rr4) {
            int row = grp + rr4 * 32;
            int node = bm0 + row;
            int sw = row & 7;
            u16x8 o0 = {}, o1 = {};
            if (s == 7) {
                if (node < NN) {
                    o0 = ((const u16x8*)hb)[(size_t)node * 16 + 2 * gl];
                    o1 = ((const u16x8*)hb)[(size_t)node * 16 + 2 * gl + 1];
                }
            } else {
                int2 sd = sSeg[row * RR + s];
                const int2* ep = edges + sd.x;
                float ac[16] = {};
                for (int i = 0; i < sd.y; ++i) {
                    int2 e = ep[i];
                    float w = __int_as_float(e.y);
                    u16x8 a = ((const u16x8*)hb)[(size_t)e.x * 16 + 2 * gl];
                    u16x8 b = ((const u16x8*)hb)[(size_t)e.x * 16 + 2 * gl + 1];
                    #pragma unroll
                    for (int j = 0; j < 8; ++j) {
                        ac[j]     += bf2f(a[j]) * w;
                        ac[8 + j] += bf2f(b[j]) * w;
                    }
                }
                #pragma unroll
                for (int j = 0; j < 8; ++j) { o0[j] = f2bf(ac[j]); o1[j] = f2bf(ac[8 + j]); }
            }
            ((u16x8*)sA)[row * 16 + ((2 * gl) ^ sw)]     = o0;
            ((u16x8*)sA)[row * 16 + ((2 * gl + 1) ^ sw)] = o1;
        }
        __syncthreads();
        // ---- MFMA: 4 k-steps of 32 over this slot ----
        #pragma unroll
        for (int k2 = 0; k2 < 4; ++k2) {
            short8 af[4], bfr[4];
            #pragma unroll
            for (int mi = 0; mi < 4; ++mi) {
                int row = wr * 64 + mi * 16 + lm;
                af[mi] = ((const short8*)sA)[row * 16 + ((k2 * 4 + lg) ^ (row & 7))];
            }
            #pragma unroll
            for (int ni = 0; ni < 4; ++ni) {
                int j = wc * 64 + ni * 16 + lm;
                bfr[ni] = *(const short8*)(Wt + (size_t)j * KK + s * 128 + k2 * 32 + lg * 8);
            }
            #pragma unroll
            for (int mi = 0; mi < 4; ++mi)
                #pragma unroll
                for (int ni = 0; ni < 4; ++ni)
                    acc[mi][ni] = __builtin_amdgcn_mfma_f32_16x16x32_bf16(af[mi], bfr[ni], acc[mi][ni], 0, 0, 0);
        }
        __syncthreads();
    }
    // ---- epilogue: bias, relu, residual; feed next layer ----
    #pragma unroll
    for (int mi = 0; mi < 4; ++mi) {
        #pragma unroll
        for (int v = 0; v < 4; ++v) {
            int gm = bm0 + wr * 64 + mi * 16 + lg * 4 + v;
            if (gm >= NN) continue;
            #pragma unroll
            for (int ni = 0; ni < 4; ++ni) {
                int n = wc * 64 + ni * 16 + lm;
                float pre = acc[mi][ni][v] + bias[n];
                float hp  = hprev[(size_t)gm * DD + n];
                float val = fmaxf(pre, 0.f) + hp;
                hout[(size_t)gm * DD + n] = val;
                if (write_next) hb_next[(size_t)gm * DD + n] = f2bf(val);
            }
        }
    }
}

__global__ void init_hb2(const float* __restrict__ x, unsigned short* __restrict__ hb) {
    int t = blockIdx.x * 256 + threadIdx.x;     // [0, NN*32)
    if (t >= NN * 32) return;
    f32x4 v = ((const f32x4*)x)[t];
    u16x8 dummy;
    unsigned short o0 = f2bf(v.x), o1 = f2bf(v.y), o2 = f2bf(v.z), o3 = f2bf(v.w);
    unsigned long long pack = (unsigned long long)o0 | ((unsigned long long)o1 << 16)
                            | ((unsigned long long)o2 << 32) | ((unsigned long long)o3 << 48);
    ((unsigned long long*)hb)[t] = pack;
    (void)dummy;
}

__global__ void zero_gf(float* gf) {
    int t = blockIdx.x * 256 + threadIdx.x;
    if (t < GG * DD) gf[t] = 0.f;
}

// Parallel readout: block = 128 nodes, 8 row-streams x 32 lanes (f32x4 cols).
__global__ __launch_bounds__(256) void readout(const float* __restrict__ h,
                                               const int* __restrict__ n2g,
                                               float* __restrict__ gf) {
    int c0 = blockIdx.x * 128;
    int rg = threadIdx.x >> 5, d4 = threadIdx.x & 31;
    f32x4 acc = {0.f, 0.f, 0.f, 0.f};
    int cur = -1;
    #pragma unroll 4
    for (int it = 0; it < 16; ++it) {
        int row = c0 + it * 8 + rg;
        if (row >= NN) break;
        int g = n2g[row];
        if (g != cur) {
            if (cur >= 0) {
                atomicAdd(&gf[cur * DD + d4 * 4 + 0], acc.x);
                atomicAdd(&gf[cur * DD + d4 * 4 + 1], acc.y);
                atomicAdd(&gf[cur * DD + d4 * 4 + 2], acc.z);
                atomicAdd(&gf[cur * DD + d4 * 4 + 3], acc.w);
            }
            cur = g;
            acc = (f32x4){0.f, 0.f, 0.f, 0.f};
        }
        acc += ((const f32x4*)h)[(size_t)row * 32 + d4];
    }
    if (cur >= 0) {
        atomicAdd(&gf[cur * DD + d4 * 4 + 0], acc.x);
        atomicAdd(&gf[cur * DD + d4 * 4 + 1], acc.y);
        atomicAdd(&gf[cur * DD + d4 * 4 + 2], acc.z);
        atomicAdd(&gf[cur * DD + d4 * 4 + 3], acc.w);
    }
}

extern "C" void kernel_launch(void* const* d_in, const int* in_sizes, int n_in,
                              void* d_out, int out_size, void* d_ws, size_t ws_size,
                              hipStream_t stream) {
    const float* x      = (const float*)d_in[0];
    const int* node_in  = (const int*)d_in[1];
    const int* node_out = (const int*)d_in[2];
    const int* relation = (const int*)d_in[3];
    const float* ew     = (const float*)d_in[4];
    const int* n2g      = (const int*)d_in[5];
    const float* sl_w[3]  = {(const float*)d_in[8],  (const float*)d_in[12], (const float*)d_in[16]};
    const float* sl_b[3]  = {(const float*)d_in[9],  (const float*)d_in[13], (const float*)d_in[17]};
    const float* lin_w[3] = {(const float*)d_in[10], (const float*)d_in[14], (const float*)d_in[18]};
    const float* lin_b[3] = {(const float*)d_in[11], (const float*)d_in[15], (const float*)d_in[19]};

    float* out = (float*)d_out;
    float* gf = out;                       // [G,D]
    float* nf = out + GG * DD;             // [N,D] node_feature (doubles as h buffer)

    char* ws = (char*)d_ws;
    size_t off = 0;
    unsigned short* hb0 = (unsigned short*)(ws + off); off += (size_t)NN * DD * 2;    // 12.8 MB
    unsigned short* hb1 = (unsigned short*)(ws + off); off += (size_t)NN * DD * 2;    // 12.8 MB
    float* hA   = (float*)(ws + off);            off += (size_t)NN * DD * 4;          // 25.6 MB
    unsigned short* Wt = (unsigned short*)(ws + off); off += (size_t)3 * KK * DD * 2;
    float* bias = (float*)(ws + off);            off += 3 * DD * 4;
    int* counts = (int*)(ws + off);              off += (size_t)NSEG * 4;
    int* cursor = (int*)(ws + off);              off += (size_t)NSEG * 4;
    int* start  = (int*)(ws + off);              off += (size_t)NSEG * 4;
    int2* segd  = (int2*)(ws + off);             off += (size_t)NSEG * 8;
    int* bsum   = (int*)(ws + off);              off += 512 * 4;
    int2* edges = (int2*)(ws + off);             off += (size_t)EE * 8;

    for (int l = 0; l < 3; ++l)
        prep_w<<<512, 256, 0, stream>>>(lin_w[l], sl_w[l], lin_b[l], sl_b[l],
                                        Wt + (size_t)l * KK * DD, bias + l * DD);

    // CSR build (edge topology is layer-invariant)
    zero_ints<<<(2 * NSEG + 255) / 256, 256, 0, stream>>>(counts, 2 * NSEG);
    hist<<<(EE + 255) / 256, 256, 0, stream>>>(node_out, relation, counts);
    scan1<<<NB1, 256, 0, stream>>>(counts, start, bsum);
    scan2<<<1, 512, 0, stream>>>(bsum);
    scan3<<<(NSEG + 255) / 256, 256, 0, stream>>>(start, bsum, counts, segd);
    fill<<<(EE + 255) / 256, 256, 0, stream>>>(node_in, node_out, relation, ew,
                                               segd, cursor, edges);
    init_hb2<<<(NN * 32) / 256, 256, 0, stream>>>(x, hb0);   // 6250 blocks exact

    const float* hcur = x;
    float* houts[3] = { nf, hA, nf };
    unsigned short* hbs[2] = { hb0, hb1 };
    for (int l = 0; l < 3; ++l) {
        fused_layer<<<(NN + BM - 1) / BM, 256, 0, stream>>>(
            hbs[l & 1], segd, edges, Wt + (size_t)l * KK * DD, bias + l * DD,
            hcur, houts[l], hbs[(l + 1) & 1], l < 2 ? 1 : 0);
        hcur = houts[l];
    }
    zero_gf<<<(GG * DD + 255) / 256, 256, 0, stream>>>(gf);
    readout<<<(NN + 127) / 128, 256, 0, stream>>>(nf, n2g, gf);
}